// Round 1
// baseline (409.559 us; speedup 1.0000x reference)
//
#include <hip/hip_runtime.h>

#define C_IMG 512
#define C_PT  256
#define IMG_H 48
#define IMG_W 160
#define HWPIX (IMG_H * IMG_W)

#define MP   64     // points per block (M tile)
#define BK   64     // K chunk
#define SPAD 72     // LDS row pitch in bf16 (64 + 8 pad, keeps 16B alignment)

typedef short bf16x8 __attribute__((ext_vector_type(8)));
typedef float f32x4  __attribute__((ext_vector_type(4)));

static __device__ __forceinline__ unsigned short f2bf(float f) {
    unsigned u = __float_as_uint(f);
    u += 0x7fffu + ((u >> 16) & 1u);   // RNE
    return (unsigned short)(u >> 16);
}
static __device__ __forceinline__ unsigned pack2(float lo, float hi) {
    return (unsigned)f2bf(lo) | ((unsigned)f2bf(hi) << 16);
}
static __device__ __forceinline__ float bflo(unsigned v) { return __uint_as_float(v << 16); }
static __device__ __forceinline__ float bfhi(unsigned v) { return __uint_as_float(v & 0xffff0000u); }

// ---------------- transpose (B,C,H,W) f32 -> (B,H*W,C) bf16 ----------------
__global__ __launch_bounds__(256)
void transpose_kernel(const float* __restrict__ img, unsigned short* __restrict__ imgT) {
    __shared__ float tile[32][33];
    const int b   = blockIdx.z;
    const int hw0 = blockIdx.x * 32;
    const int c0  = blockIdx.y * 32;
    const int tx  = threadIdx.x;      // 0..31
    const int ty  = threadIdx.y;      // 0..7
    const float* src = img + (size_t)b * C_IMG * HWPIX;
    #pragma unroll
    for (int i = 0; i < 32; i += 8)
        tile[ty + i][tx] = src[(size_t)(c0 + ty + i) * HWPIX + hw0 + tx];
    __syncthreads();
    unsigned short* dst = imgT + (size_t)b * HWPIX * C_IMG;
    #pragma unroll
    for (int i = 0; i < 32; i += 8)
        dst[(size_t)(hw0 + ty + i) * C_IMG + c0 + tx] = f2bf(tile[tx][ty + i]);
}

// ---------------- fused gather + GEMM + epilogue ----------------
template<bool TRANS>
__global__ __launch_bounds__(256)
void fused_kernel(const float* __restrict__ pf,
                  const float* __restrict__ centers,
                  const void*  __restrict__ imgv,
                  const float* __restrict__ P2,
                  const float* __restrict__ R0,
                  const float* __restrict__ Tr,
                  const float* __restrict__ alw,
                  const float* __restrict__ alb,
                  const int*   __restrict__ bidx,
                  float* __restrict__ out,
                  int n)
{
    __shared__ float          sWg[MP][4];
    __shared__ int            sOf[MP][4];
    __shared__ unsigned short sS[MP][SPAD];     // sampled tile, bf16
    __shared__ unsigned short sW[C_PT][SPAD];   // align_w tile, bf16 (layout [n][k])

    const int tid = threadIdx.x;
    const int pt0 = blockIdx.x * MP;

    // ---- per-point projection (threads 0..63) ----
    if (tid < MP) {
        const int p = pt0 + tid;
        float w[4] = {0.f, 0.f, 0.f, 0.f};
        int   o[4] = {0, 0, 0, 0};
        if (p < n) {
            const float cx = centers[p * 3 + 0];
            const float cy = centers[p * 3 + 1];
            const float cz = centers[p * 3 + 2];
            const int   b  = bidx[p];
            const float* tr = Tr + b * 16;
            const float c0 = tr[0]*cx + tr[1]*cy + tr[2]*cz + tr[3];
            const float c1 = tr[4]*cx + tr[5]*cy + tr[6]*cz + tr[7];
            const float c2 = tr[8]*cx + tr[9]*cy + tr[10]*cz + tr[11];
            const float c3 = tr[12]*cx + tr[13]*cy + tr[14]*cz + tr[15];
            const float* r0 = R0 + b * 16;
            const float e0 = r0[0]*c0 + r0[1]*c1 + r0[2]*c2 + r0[3]*c3;
            const float e1 = r0[4]*c0 + r0[5]*c1 + r0[6]*c2 + r0[7]*c3;
            const float e2 = r0[8]*c0 + r0[9]*c1 + r0[10]*c2 + r0[11]*c3;
            const float e3 = r0[12]*c0 + r0[13]*c1 + r0[14]*c2 + r0[15]*c3;
            const float* p2 = P2 + b * 12;
            const float ix = p2[0]*e0 + p2[1]*e1 + p2[2]*e2  + p2[3]*e3;
            const float iy = p2[4]*e0 + p2[5]*e1 + p2[6]*e2  + p2[7]*e3;
            const float iz = p2[8]*e0 + p2[9]*e1 + p2[10]*e2 + p2[11]*e3;
            const float depth = fmaxf(iz, 1e-5f);
            const float u = ix / depth;
            const float v = iy / depth;
            const bool valid = (iz > 0.f) && (u >= 0.f) && (u < (float)IMG_W)
                                         && (v >= 0.f) && (v < (float)IMG_H);
            const float x0f = floorf(u), y0f = floorf(v);
            const float wx1 = u - x0f, wx0 = 1.f - wx1;
            const float wy1 = v - y0f, wy0 = 1.f - wy1;
            const float cw[4] = {wx0 * wy0, wx1 * wy0, wx0 * wy1, wx1 * wy1};
            #pragma unroll
            for (int j = 0; j < 4; ++j) {
                const float xf = x0f + (float)(j & 1);
                const float yf = y0f + (float)(j >> 1);
                const bool inb = (xf >= 0.f) && (xf <= (float)(IMG_W - 1))
                              && (yf >= 0.f) && (yf <= (float)(IMG_H - 1));
                const int xc = (int)fminf(fmaxf(xf, 0.f), (float)(IMG_W - 1));
                const int yc = (int)fminf(fmaxf(yf, 0.f), (float)(IMG_H - 1));
                w[j] = (valid && inb) ? cw[j] : 0.f;
                o[j] = TRANS ? ((b * IMG_H + yc) * IMG_W + xc) * C_IMG
                             : b * C_IMG * HWPIX + yc * IMG_W + xc;
            }
        }
        #pragma unroll
        for (int j = 0; j < 4; ++j) { sWg[tid][j] = w[j]; sOf[tid][j] = o[j]; }
    }

    f32x4 acc[4][4];
    #pragma unroll
    for (int i = 0; i < 4; ++i)
        #pragma unroll
        for (int j = 0; j < 4; ++j)
            acc[i][j] = (f32x4){0.f, 0.f, 0.f, 0.f};

    const int lane = tid & 63;
    const int wid  = tid >> 6;
    const int l15  = lane & 15;
    const int quad = lane >> 4;
    const int sp   = tid >> 2;   // staging: point index
    const int ssub = tid & 3;    // staging: 16-channel sub-chunk

    __syncthreads();

    for (int ck = 0; ck < C_IMG / BK; ++ck) {
        // ---- stage sampled tile: 4 threads/point, 16 channels each ----
        {
            const float cw0 = sWg[sp][0], cw1 = sWg[sp][1], cw2 = sWg[sp][2], cw3 = sWg[sp][3];
            const int   co0 = sOf[sp][0], co1 = sOf[sp][1], co2 = sOf[sp][2], co3 = sOf[sp][3];
            const int   cb  = ck * BK + ssub * 16;
            if (TRANS) {
                const unsigned short* ib = (const unsigned short*)imgv;
                #pragma unroll
                for (int h = 0; h < 2; ++h) {
                    const uint4 q0 = *(const uint4*)(ib + co0 + cb + h * 8);
                    const uint4 q1 = *(const uint4*)(ib + co1 + cb + h * 8);
                    const uint4 q2 = *(const uint4*)(ib + co2 + cb + h * 8);
                    const uint4 q3 = *(const uint4*)(ib + co3 + cb + h * 8);
                    const unsigned* u0 = (const unsigned*)&q0;
                    const unsigned* u1 = (const unsigned*)&q1;
                    const unsigned* u2 = (const unsigned*)&q2;
                    const unsigned* u3 = (const unsigned*)&q3;
                    uint4 ov;
                    unsigned* op = (unsigned*)&ov;
                    #pragma unroll
                    for (int wI = 0; wI < 4; ++wI) {
                        const float vlo = cw0*bflo(u0[wI]) + cw1*bflo(u1[wI]) + cw2*bflo(u2[wI]) + cw3*bflo(u3[wI]);
                        const float vhi = cw0*bfhi(u0[wI]) + cw1*bfhi(u1[wI]) + cw2*bfhi(u2[wI]) + cw3*bfhi(u3[wI]);
                        op[wI] = pack2(vlo, vhi);
                    }
                    *(uint4*)&sS[sp][ssub * 16 + h * 8] = ov;
                }
            } else {
                const float* ib = (const float*)imgv;
                #pragma unroll
                for (int h = 0; h < 2; ++h) {
                    uint4 ov;
                    unsigned* op = (unsigned*)&ov;
                    #pragma unroll
                    for (int wI = 0; wI < 4; ++wI) {
                        const int c = cb + h * 8 + 2 * wI;
                        const float vlo = cw0*ib[co0 + c*HWPIX] + cw1*ib[co1 + c*HWPIX]
                                        + cw2*ib[co2 + c*HWPIX] + cw3*ib[co3 + c*HWPIX];
                        const float vhi = cw0*ib[co0 + (c+1)*HWPIX] + cw1*ib[co1 + (c+1)*HWPIX]
                                        + cw2*ib[co2 + (c+1)*HWPIX] + cw3*ib[co3 + (c+1)*HWPIX];
                        op[wI] = pack2(vlo, vhi);
                    }
                    *(uint4*)&sS[sp][ssub * 16 + h * 8] = ov;
                }
            }
        }
        // ---- stage align_w tile: [n][k] layout, fp32 -> bf16 ----
        {
            #pragma unroll
            for (int pass = 0; pass < 4; ++pass) {
                const int r = pass * 64 + (tid >> 2);
                const int c = (tid & 3) * 16;
                const float* wr = alw + (size_t)r * C_IMG + ck * BK + c;
                const float4 f0 = *(const float4*)(wr + 0);
                const float4 f1 = *(const float4*)(wr + 4);
                const float4 f2 = *(const float4*)(wr + 8);
                const float4 f3 = *(const float4*)(wr + 12);
                uint4 oa, ob;
                oa.x = pack2(f0.x, f0.y); oa.y = pack2(f0.z, f0.w);
                oa.z = pack2(f1.x, f1.y); oa.w = pack2(f1.z, f1.w);
                ob.x = pack2(f2.x, f2.y); ob.y = pack2(f2.z, f2.w);
                ob.z = pack2(f3.x, f3.y); ob.w = pack2(f3.z, f3.w);
                *(uint4*)&sW[r][c]     = oa;
                *(uint4*)&sW[r][c + 8] = ob;
            }
        }
        __syncthreads();

        // ---- MFMA: each wave owns 64 points x 64 out-channels ----
        #pragma unroll
        for (int kk = 0; kk < 2; ++kk) {
            bf16x8 af[4], bfr[4];
            #pragma unroll
            for (int mt = 0; mt < 4; ++mt)
                af[mt] = *(const bf16x8*)&sS[mt * 16 + l15][kk * 32 + quad * 8];
            #pragma unroll
            for (int nt = 0; nt < 4; ++nt)
                bfr[nt] = *(const bf16x8*)&sW[wid * 64 + nt * 16 + l15][kk * 32 + quad * 8];
            #pragma unroll
            for (int mt = 0; mt < 4; ++mt)
                #pragma unroll
                for (int nt = 0; nt < 4; ++nt)
                    acc[mt][nt] = __builtin_amdgcn_mfma_f32_16x16x32_bf16(
                        af[mt], bfr[nt], acc[mt][nt], 0, 0, 0);
        }
        __syncthreads();
    }

    // ---- epilogue: out = point_feat + bias + acc ----
    // C/D layout (16x16): col = lane&15 (n), row = quad*4 + reg (m)
    #pragma unroll
    for (int mt = 0; mt < 4; ++mt) {
        #pragma unroll
        for (int r = 0; r < 4; ++r) {
            const int p = pt0 + mt * 16 + quad * 4 + r;
            if (p < n) {
                #pragma unroll
                for (int nt = 0; nt < 4; ++nt) {
                    const int nc = wid * 64 + nt * 16 + l15;
                    const size_t idx = (size_t)p * C_PT + nc;
                    out[idx] = pf[idx] + alb[nc] + acc[mt][nt][r];
                }
            }
        }
    }
}

extern "C" void kernel_launch(void* const* d_in, const int* in_sizes, int n_in,
                              void* d_out, int out_size, void* d_ws, size_t ws_size,
                              hipStream_t stream) {
    const float* pf      = (const float*)d_in[0];
    const float* centers = (const float*)d_in[1];
    const float* img     = (const float*)d_in[2];
    const float* P2      = (const float*)d_in[3];
    const float* R0      = (const float*)d_in[4];
    const float* Tr      = (const float*)d_in[5];
    const float* alw     = (const float*)d_in[6];
    const float* alb     = (const float*)d_in[7];
    const int*   bidx    = (const int*)d_in[8];
    float*       out     = (float*)d_out;

    const int n  = in_sizes[8];           // 100000 points
    const int bs = in_sizes[3] / 12;      // P2 is (BS,3,4)
    const int nblk = (n + MP - 1) / MP;

    const size_t tneed = (size_t)bs * HWPIX * C_IMG * sizeof(unsigned short);
    if (ws_size >= tneed) {
        unsigned short* imgT = (unsigned short*)d_ws;
        dim3 tg(HWPIX / 32, C_IMG / 32, bs);
        transpose_kernel<<<tg, dim3(32, 8), 0, stream>>>(img, imgT);
        fused_kernel<true><<<nblk, 256, 0, stream>>>(
            pf, centers, (const void*)imgT, P2, R0, Tr, alw, alb, bidx, out, n);
    } else {
        fused_kernel<false><<<nblk, 256, 0, stream>>>(
            pf, centers, (const void*)img, P2, R0, Tr, alw, alb, bidx, out, n);
    }
}